// Round 1
// baseline (325.838 us; speedup 1.0000x reference)
//
#include <hip/hip_runtime.h>

// GConv: out = spmm(A0, S) + spmm(A1, S) + bias,  S = x @ W
// N=100000, E=600000, F_IN=F_OUT=128.
// R6: pull_rec was latency-bound on the serial linked-list chain walk
//     (12 dependent rec loads/row; VALUBusy 16.6%, HBM 24.5%). Replace
//     chains with CSR via counting sort:
//       - rec shrinks 16B (next,col,val) -> 8B (col,val), contiguous per row
//       - whole row edge list fetched in ONE coalesced lane-parallel load,
//         broadcast via __shfl
//       - support gathers issued 4-wide (independent) -> MLP ~4-8 per wave

#define FDIM 128

typedef __attribute__((ext_vector_type(8))) short short8;
typedef __attribute__((ext_vector_type(4))) float floatx4;

__device__ __forceinline__ unsigned short f32_to_bf16(float f) {
    unsigned int u = __float_as_uint(f);
    unsigned int r = u + 0x7fffu + ((u >> 16) & 1u);   // RNE
    return (unsigned short)(r >> 16);
}

__device__ __forceinline__ float bf16_lo(unsigned int u) {
    return __uint_as_float((u & 0xffffu) << 16);
}
__device__ __forceinline__ float bf16_hi(unsigned int u) {
    return __uint_as_float(u & 0xffff0000u);
}

// ---------------- Wt[n][k] = bf16(W[k][n]) — 64KB, one-shot ----------------
__global__ __launch_bounds__(256) void wt_conv(const float* __restrict__ w,
                                               unsigned short* __restrict__ wt) {
    int idx = blockIdx.x * 256 + threadIdx.x;   // 0..16383
    int nn = idx >> 7, k = idx & 127;
    wt[idx] = f32_to_bf16(w[(size_t)k * FDIM + nn]);
}

// ---------------- GEMM: support(bf16) = x @ W via MFMA ---------------------
// 64 rows x 128 cols per block; As/Bs staged with coalesced 16B copies.
__global__ __launch_bounds__(256) void gemm_mfma(const float* __restrict__ x,
                                                 const unsigned short* __restrict__ wt,
                                                 unsigned short* __restrict__ support,
                                                 int n) {
    __shared__ __align__(16) short As[64][136];    // As[m][k], pitch 272B
    __shared__ __align__(16) short Bs[128][136];   // Bs[n][k]
    const int tid = threadIdx.x;
    const int m0 = blockIdx.x * 64;

    #pragma unroll
    for (int i = 0; i < 8; ++i) {
        int idx = tid + i * 256;          // 0..2047 float4 chunks
        int r = idx >> 5, c4 = idx & 31;
        float4 v = make_float4(0.f, 0.f, 0.f, 0.f);
        if (m0 + r < n) v = *(const float4*)(x + (size_t)(m0 + r) * FDIM + c4 * 4);
        short4 s;
        s.x = (short)f32_to_bf16(v.x); s.y = (short)f32_to_bf16(v.y);
        s.z = (short)f32_to_bf16(v.z); s.w = (short)f32_to_bf16(v.w);
        *(short4*)&As[r][c4 * 4] = s;
    }
    #pragma unroll
    for (int i = 0; i < 8; ++i) {
        int idx = tid + i * 256;          // 0..2047 short8 chunks
        int r = idx >> 4, c8 = idx & 15;
        short8 v = *(const short8*)(wt + (size_t)r * FDIM + c8 * 8);
        *(short8*)&Bs[r][c8 * 8] = v;
    }
    __syncthreads();

    const int wv = tid >> 6;
    const int lane = tid & 63;
    const int quad = lane >> 4;
    const int lr = lane & 15;

    floatx4 acc[8];
    #pragma unroll
    for (int nt = 0; nt < 8; ++nt) acc[nt] = (floatx4)0.f;

    #pragma unroll
    for (int ks = 0; ks < 4; ++ks) {
        short8 a = *(const short8*)&As[wv * 16 + lr][ks * 32 + quad * 8];
        #pragma unroll
        for (int nt = 0; nt < 8; ++nt) {
            short8 b = *(const short8*)&Bs[nt * 16 + lr][ks * 32 + quad * 8];
            acc[nt] = __builtin_amdgcn_mfma_f32_16x16x32_bf16(a, b, acc[nt], 0, 0, 0);
        }
    }

    #pragma unroll
    for (int i = 0; i < 4; ++i) {
        int row = m0 + wv * 16 + quad * 4 + i;
        if (row < n) {
            #pragma unroll
            for (int nt = 0; nt < 8; ++nt)
                support[(size_t)row * FDIM + nt * 16 + lr] = f32_to_bf16(acc[nt][i]);
        }
    }
}

// ---------------- CSR build: hist -> scan -> scatter -----------------------
__global__ __launch_bounds__(256) void hist_rows(const int* __restrict__ rows0,
                                                 const int* __restrict__ rows1,
                                                 int* __restrict__ count, int E) {
    int gid = blockIdx.x * 256 + threadIdx.x;
    if (gid >= 2 * E) return;
    int r = (gid < E) ? rows0[gid] : rows1[gid - E];
    atomicAdd(&count[r], 1);
}

// block-wide inclusive scan of v over 256 threads (lds must hold 8 ints)
__device__ __forceinline__ int block_incl_scan(int v, int tid, int* lds) {
    int lane = tid & 63, wv = tid >> 6;
    #pragma unroll
    for (int d = 1; d < 64; d <<= 1) {
        int y = __shfl_up(v, d);
        if (lane >= d) v += y;
    }
    if (lane == 63) lds[wv] = v;
    __syncthreads();
    if (wv == 0 && lane < 4) {
        int s = lds[lane];
        #pragma unroll
        for (int d = 1; d < 4; d <<= 1) {
            int y = __shfl_up(s, d);
            if (lane >= d) s += y;
        }
        lds[4 + lane] = s;
    }
    __syncthreads();
    int add = (wv > 0) ? lds[4 + wv - 1] : 0;
    return v + add;
}

__global__ __launch_bounds__(256) void block_sum(const int* __restrict__ count,
                                                 int* __restrict__ bsum, int n) {
    __shared__ int lds[8];
    int tid = threadIdx.x;
    int idx = blockIdx.x * 256 + tid;
    int v = (idx < n) ? count[idx] : 0;
    int inc = block_incl_scan(v, tid, lds);
    if (tid == 255) bsum[blockIdx.x] = inc;
}

__global__ __launch_bounds__(256) void scan_bsum(int* __restrict__ bsum, int nb) {
    __shared__ int lds[8];
    __shared__ int carry;
    int tid = threadIdx.x;
    if (tid == 0) carry = 0;
    __syncthreads();
    for (int base = 0; base < nb; base += 256) {
        int i = base + tid;
        int v = (i < nb) ? bsum[i] : 0;
        int inc = block_incl_scan(v, tid, lds);
        int c = carry;                      // read before barrier
        if (i < nb) bsum[i] = c + inc - v;  // exclusive
        __syncthreads();
        if (tid == 255) carry = c + inc;    // chunk total
        __syncthreads();
    }
}

__global__ __launch_bounds__(256) void write_ptr(const int* __restrict__ count,
                                                 const int* __restrict__ bscan,
                                                 int* __restrict__ rowptr,
                                                 int* __restrict__ cursor,
                                                 int n, int total) {
    __shared__ int lds[8];
    int tid = threadIdx.x;
    int idx = blockIdx.x * 256 + tid;
    int v = (idx < n) ? count[idx] : 0;
    int inc = block_incl_scan(v, tid, lds);
    if (idx < n) {
        int p = bscan[blockIdx.x] + inc - v;
        rowptr[idx] = p;
        cursor[idx] = p;
    }
    if (idx == 0) rowptr[n] = total;
}

__global__ __launch_bounds__(256) void scatter_rec(const int* __restrict__ rows0,
                                                   const int* __restrict__ cols0,
                                                   const float* __restrict__ vals0,
                                                   const int* __restrict__ rows1,
                                                   const int* __restrict__ cols1,
                                                   const float* __restrict__ vals1,
                                                   int* __restrict__ cursor,
                                                   int2* __restrict__ rec, int E) {
    int gid = blockIdx.x * 256 + threadIdx.x;
    if (gid >= 2 * E) return;
    int r, c; float v;
    if (gid < E) { r = rows0[gid]; c = cols0[gid]; v = vals0[gid]; }
    else         { int e = gid - E; r = rows1[e]; c = cols1[e]; v = vals1[e]; }
    int pos = atomicAdd(&cursor[r], 1);
    rec[pos] = make_int2(c, __float_as_int(v));
}

// ---------------- pull: wave per row; coalesced rec load + shfl broadcast --
__global__ __launch_bounds__(256) void pull_csr(const unsigned short* __restrict__ support,
                                                const int* __restrict__ rowptr,
                                                const int2* __restrict__ rec,
                                                const float* __restrict__ bias,
                                                float* __restrict__ out, int n) {
    int wid = (blockIdx.x * 256 + threadIdx.x) >> 6;
    int lane = threadIdx.x & 63;
    if (wid >= n) return;
    int beg = rowptr[wid], end = rowptr[wid + 1];
    float ax = 0.f, ay = 0.f;
    const char* sp = (const char*)support;
    const unsigned loff = (unsigned)lane << 2;   // lane*4 bytes = 2 bf16 feats

    for (int base = beg; base < end; base += 64) {
        int m = end - base; if (m > 64) m = 64;
        long long pk = 0;
        if (lane < m) pk = *(const long long*)&rec[base + lane];  // 1 coalesced load
        int j = 0;
        for (; j + 4 <= m; j += 4) {
            long long p0 = __shfl(pk, j);
            long long p1 = __shfl(pk, j + 1);
            long long p2 = __shfl(pk, j + 2);
            long long p3 = __shfl(pk, j + 3);
            unsigned u0 = *(const unsigned*)(sp + (((unsigned)p0) << 8) + loff);
            unsigned u1 = *(const unsigned*)(sp + (((unsigned)p1) << 8) + loff);
            unsigned u2 = *(const unsigned*)(sp + (((unsigned)p2) << 8) + loff);
            unsigned u3 = *(const unsigned*)(sp + (((unsigned)p3) << 8) + loff);
            float v0 = __int_as_float((int)(p0 >> 32));
            float v1 = __int_as_float((int)(p1 >> 32));
            float v2 = __int_as_float((int)(p2 >> 32));
            float v3 = __int_as_float((int)(p3 >> 32));
            ax += v0 * bf16_lo(u0); ay += v0 * bf16_hi(u0);
            ax += v1 * bf16_lo(u1); ay += v1 * bf16_hi(u1);
            ax += v2 * bf16_lo(u2); ay += v2 * bf16_hi(u2);
            ax += v3 * bf16_lo(u3); ay += v3 * bf16_hi(u3);
        }
        for (; j < m; ++j) {
            long long p = __shfl(pk, j);
            unsigned u = *(const unsigned*)(sp + (((unsigned)p) << 8) + loff);
            float v = __int_as_float((int)(p >> 32));
            ax += v * bf16_lo(u); ay += v * bf16_hi(u);
        }
    }
    float2 b = *(const float2*)(bias + lane * 2);
    *(float2*)(out + (size_t)wid * FDIM + lane * 2) = make_float2(ax + b.x, ay + b.y);
}

// ---------------- fallback (ws too small): atomic scatter ------------------
__global__ __launch_bounds__(256) void init_bias(const float* __restrict__ bias,
                                                 float* __restrict__ out, int n) {
    int idx = blockIdx.x * 256 + threadIdx.x;
    int total = n * (FDIM / 4);
    if (idx < total) {
        int j = (idx & (FDIM / 4 - 1)) * 4;
        float4 b = *(const float4*)(bias + j);
        *(float4*)(out + (size_t)idx * 4) = b;
    }
}

__global__ __launch_bounds__(256) void scatter_bf16(
    const unsigned short* __restrict__ support,
    const int* __restrict__ rows0, const int* __restrict__ cols0, const float* __restrict__ vals0,
    const int* __restrict__ rows1, const int* __restrict__ cols1, const float* __restrict__ vals1,
    float* __restrict__ out, int E) {
    int gid = blockIdx.x * 256 + threadIdx.x;
    int lane = gid & 63;
    int eg = gid >> 6;
    if (eg >= 2 * E) return;
    int r, c; float v;
    if (eg < E) { r = rows0[eg]; c = cols0[eg]; v = vals0[eg]; }
    else        { int e = eg - E; r = rows1[e]; c = cols1[e]; v = vals1[e]; }
    unsigned int u = *(const unsigned int*)(support + (size_t)c * FDIM + lane * 2);
    float sx = bf16_lo(u);
    float sy = bf16_hi(u);
    float* op = out + (size_t)r * FDIM + lane * 2;
    atomicAdd(op,     sx * v);
    atomicAdd(op + 1, sy * v);
}

static inline size_t align256(size_t v) { return (v + 255) & ~(size_t)255; }

extern "C" void kernel_launch(void* const* d_in, const int* in_sizes, int n_in,
                              void* d_out, int out_size, void* d_ws, size_t ws_size,
                              hipStream_t stream) {
    const float* x     = (const float*)d_in[0];
    const float* w     = (const float*)d_in[1];
    const float* bias  = (const float*)d_in[2];
    const float* vals0 = (const float*)d_in[3];
    const float* vals1 = (const float*)d_in[4];
    const int*   rows0 = (const int*)d_in[5];
    const int*   cols0 = (const int*)d_in[6];
    const int*   rows1 = (const int*)d_in[7];
    const int*   cols1 = (const int*)d_in[8];
    const int n = in_sizes[0] / FDIM;
    const int E = in_sizes[3];
    float* out = (float*)d_out;

    const int NB = (n + 255) / 256;

    size_t off = 0;
    unsigned short* support = (unsigned short*)((char*)d_ws + off);
    off = align256(off + (size_t)n * FDIM * 2);
    unsigned short* wt = (unsigned short*)((char*)d_ws + off);
    off = align256(off + (size_t)FDIM * FDIM * 2);
    int*  count  = (int*)((char*)d_ws + off);  off = align256(off + (size_t)n * 4);
    int*  rowptr = (int*)((char*)d_ws + off);  off = align256(off + (size_t)(n + 1) * 4);
    int*  cursor = (int*)((char*)d_ws + off);  off = align256(off + (size_t)n * 4);
    int*  bsum   = (int*)((char*)d_ws + off);  off = align256(off + (size_t)NB * 4);
    int2* rec    = (int2*)((char*)d_ws + off); off = align256(off + (size_t)2 * E * 8);

    wt_conv<<<(FDIM * FDIM) / 256, 256, 0, stream>>>(w, wt);
    gemm_mfma<<<(n + 63) / 64, 256, 0, stream>>>(x, wt, support, n);

    if (off <= ws_size) {
        hipMemsetAsync(count, 0, (size_t)n * 4, stream);
        int eb = (2 * E + 255) / 256;
        hist_rows<<<eb, 256, 0, stream>>>(rows0, rows1, count, E);
        block_sum<<<NB, 256, 0, stream>>>(count, bsum, n);
        scan_bsum<<<1, 256, 0, stream>>>(bsum, NB);
        write_ptr<<<NB, 256, 0, stream>>>(count, bsum, rowptr, cursor, n, 2 * E);
        scatter_rec<<<eb, 256, 0, stream>>>(rows0, cols0, vals0, rows1, cols1, vals1,
                                            cursor, rec, E);
        pull_csr<<<(n + 3) / 4, 256, 0, stream>>>(support, rowptr, rec, bias, out, n);
    } else {
        int total4 = n * (FDIM / 4);
        init_bias<<<(total4 + 255) / 256, 256, 0, stream>>>(bias, out, n);
        long long tthreads = 2LL * E * 64;
        int blocks = (int)((tthreads + 255) / 256);
        scatter_bf16<<<blocks, 256, 0, stream>>>(support, rows0, cols0, vals0,
                                                 rows1, cols1, vals1, out, E);
    }
}

// Round 2
// 278.227 us; speedup vs baseline: 1.1711x; 1.1711x over previous
//
#include <hip/hip_runtime.h>

// GConv: out = spmm(A0, S) + spmm(A1, S) + bias,  S = x @ W
// N=100000, E=600000, F_IN=F_OUT=128.
// R7: scatter_rec was the new top dispatch (~104us): 8B random stores ->
//     76.8MB un-merged line writebacks (edges of one row processed far apart
//     in time on different XCDs; per-XCD L2s flush partial lines separately)
//     + a dependent cursor atomic per edge.
//     (1) rank-from-hist: hist's atomicAdd return value IS the edge's rank
//         within its row -> scatter pos = rowptr[r] + rank[gid], no atomic.
//     (2) XCD-partitioned scatter: block b writes only rows in partition b&7
//         (tile b>>3). Dispatch round-robins blocks over 8 XCDs, so each rec
//         partition region (~1.2MB) is written by one XCD -> dirty lines
//         merge in its L2 and write back once (~9.6MB instead of 77MB).
//         Correct for ANY block->XCD mapping (each edge matches exactly one
//         partition).

#define FDIM 128
#define EPB 2048   // edges examined per scatter block

typedef __attribute__((ext_vector_type(8))) short short8;
typedef __attribute__((ext_vector_type(4))) float floatx4;

__device__ __forceinline__ unsigned short f32_to_bf16(float f) {
    unsigned int u = __float_as_uint(f);
    unsigned int r = u + 0x7fffu + ((u >> 16) & 1u);   // RNE
    return (unsigned short)(r >> 16);
}

__device__ __forceinline__ float bf16_lo(unsigned int u) {
    return __uint_as_float((u & 0xffffu) << 16);
}
__device__ __forceinline__ float bf16_hi(unsigned int u) {
    return __uint_as_float(u & 0xffff0000u);
}

// ---------------- Wt[n][k] = bf16(W[k][n]) — 64KB, one-shot ----------------
__global__ __launch_bounds__(256) void wt_conv(const float* __restrict__ w,
                                               unsigned short* __restrict__ wt) {
    int idx = blockIdx.x * 256 + threadIdx.x;   // 0..16383
    int nn = idx >> 7, k = idx & 127;
    wt[idx] = f32_to_bf16(w[(size_t)k * FDIM + nn]);
}

// ---------------- GEMM: support(bf16) = x @ W via MFMA ---------------------
__global__ __launch_bounds__(256) void gemm_mfma(const float* __restrict__ x,
                                                 const unsigned short* __restrict__ wt,
                                                 unsigned short* __restrict__ support,
                                                 int n) {
    __shared__ __align__(16) short As[64][136];    // As[m][k], pitch 272B
    __shared__ __align__(16) short Bs[128][136];   // Bs[n][k]
    const int tid = threadIdx.x;
    const int m0 = blockIdx.x * 64;

    #pragma unroll
    for (int i = 0; i < 8; ++i) {
        int idx = tid + i * 256;          // 0..2047 float4 chunks
        int r = idx >> 5, c4 = idx & 31;
        float4 v = make_float4(0.f, 0.f, 0.f, 0.f);
        if (m0 + r < n) v = *(const float4*)(x + (size_t)(m0 + r) * FDIM + c4 * 4);
        short4 s;
        s.x = (short)f32_to_bf16(v.x); s.y = (short)f32_to_bf16(v.y);
        s.z = (short)f32_to_bf16(v.z); s.w = (short)f32_to_bf16(v.w);
        *(short4*)&As[r][c4 * 4] = s;
    }
    #pragma unroll
    for (int i = 0; i < 8; ++i) {
        int idx = tid + i * 256;          // 0..2047 short8 chunks
        int r = idx >> 4, c8 = idx & 15;
        short8 v = *(const short8*)(wt + (size_t)r * FDIM + c8 * 8);
        *(short8*)&Bs[r][c8 * 8] = v;
    }
    __syncthreads();

    const int wv = tid >> 6;
    const int lane = tid & 63;
    const int quad = lane >> 4;
    const int lr = lane & 15;

    floatx4 acc[8];
    #pragma unroll
    for (int nt = 0; nt < 8; ++nt) acc[nt] = (floatx4)0.f;

    #pragma unroll
    for (int ks = 0; ks < 4; ++ks) {
        short8 a = *(const short8*)&As[wv * 16 + lr][ks * 32 + quad * 8];
        #pragma unroll
        for (int nt = 0; nt < 8; ++nt) {
            short8 b = *(const short8*)&Bs[nt * 16 + lr][ks * 32 + quad * 8];
            acc[nt] = __builtin_amdgcn_mfma_f32_16x16x32_bf16(a, b, acc[nt], 0, 0, 0);
        }
    }

    #pragma unroll
    for (int i = 0; i < 4; ++i) {
        int row = m0 + wv * 16 + quad * 4 + i;
        if (row < n) {
            #pragma unroll
            for (int nt = 0; nt < 8; ++nt)
                support[(size_t)row * FDIM + nt * 16 + lr] = f32_to_bf16(acc[nt][i]);
        }
    }
}

// ---------------- CSR build: hist(+rank) -> scan -> partitioned scatter ----
__global__ __launch_bounds__(256) void hist_rows(const int* __restrict__ rows0,
                                                 const int* __restrict__ rows1,
                                                 int* __restrict__ count,
                                                 int* __restrict__ rank, int E) {
    int gid = blockIdx.x * 256 + threadIdx.x;
    if (gid >= 2 * E) return;
    int r = (gid < E) ? rows0[gid] : rows1[gid - E];
    rank[gid] = atomicAdd(&count[r], 1);   // returned old value = rank in row
}

// block-wide inclusive scan of v over 256 threads (lds must hold 8 ints)
__device__ __forceinline__ int block_incl_scan(int v, int tid, int* lds) {
    int lane = tid & 63, wv = tid >> 6;
    #pragma unroll
    for (int d = 1; d < 64; d <<= 1) {
        int y = __shfl_up(v, d);
        if (lane >= d) v += y;
    }
    if (lane == 63) lds[wv] = v;
    __syncthreads();
    if (wv == 0 && lane < 4) {
        int s = lds[lane];
        #pragma unroll
        for (int d = 1; d < 4; d <<= 1) {
            int y = __shfl_up(s, d);
            if (lane >= d) s += y;
        }
        lds[4 + lane] = s;
    }
    __syncthreads();
    int add = (wv > 0) ? lds[4 + wv - 1] : 0;
    return v + add;
}

__global__ __launch_bounds__(256) void block_sum(const int* __restrict__ count,
                                                 int* __restrict__ bsum, int n) {
    __shared__ int lds[8];
    int tid = threadIdx.x;
    int idx = blockIdx.x * 256 + tid;
    int v = (idx < n) ? count[idx] : 0;
    int inc = block_incl_scan(v, tid, lds);
    if (tid == 255) bsum[blockIdx.x] = inc;
}

__global__ __launch_bounds__(256) void scan_bsum(int* __restrict__ bsum, int nb) {
    __shared__ int lds[8];
    __shared__ int carry;
    int tid = threadIdx.x;
    if (tid == 0) carry = 0;
    __syncthreads();
    for (int base = 0; base < nb; base += 256) {
        int i = base + tid;
        int v = (i < nb) ? bsum[i] : 0;
        int inc = block_incl_scan(v, tid, lds);
        int c = carry;                      // read before barrier
        if (i < nb) bsum[i] = c + inc - v;  // exclusive
        __syncthreads();
        if (tid == 255) carry = c + inc;    // chunk total
        __syncthreads();
    }
}

__global__ __launch_bounds__(256) void write_ptr(const int* __restrict__ count,
                                                 const int* __restrict__ bscan,
                                                 int* __restrict__ rowptr,
                                                 int n, int total) {
    __shared__ int lds[8];
    int tid = threadIdx.x;
    int idx = blockIdx.x * 256 + tid;
    int v = (idx < n) ? count[idx] : 0;
    int inc = block_incl_scan(v, tid, lds);
    if (idx < n) rowptr[idx] = bscan[blockIdx.x] + inc - v;
    if (idx == 0) rowptr[n] = total;
}

// block b: edge tile b>>3, row-partition b&7. Each edge matches exactly one
// partition -> written once, by (mostly) one XCD -> L2-merged writebacks.
__global__ __launch_bounds__(256) void scatter_part(
    const int* __restrict__ rows0, const int* __restrict__ cols0, const float* __restrict__ vals0,
    const int* __restrict__ rows1, const int* __restrict__ cols1, const float* __restrict__ vals1,
    const int* __restrict__ rank, const int* __restrict__ rowptr,
    int2* __restrict__ rec, int E, int nper) {
    const int p = blockIdx.x & 7;
    const int base = (blockIdx.x >> 3) * EPB;
    const int tid = threadIdx.x;
    #pragma unroll
    for (int it = 0; it < EPB / 256; ++it) {
        int gid = base + it * 256 + tid;
        if (gid < 2 * E) {
            int r = (gid < E) ? rows0[gid] : rows1[gid - E];
            if (r / nper == p) {
                int c; float v;
                if (gid < E) { c = cols0[gid]; v = vals0[gid]; }
                else         { int e = gid - E; c = cols1[e]; v = vals1[e]; }
                int pos = rowptr[r] + rank[gid];
                rec[pos] = make_int2(c, __float_as_int(v));
            }
        }
    }
}

// ---------------- pull: wave per row; coalesced rec load + shfl broadcast --
__global__ __launch_bounds__(256) void pull_csr(const unsigned short* __restrict__ support,
                                                const int* __restrict__ rowptr,
                                                const int2* __restrict__ rec,
                                                const float* __restrict__ bias,
                                                float* __restrict__ out, int n) {
    int wid = (blockIdx.x * 256 + threadIdx.x) >> 6;
    int lane = threadIdx.x & 63;
    if (wid >= n) return;
    int beg = rowptr[wid], end = rowptr[wid + 1];
    float ax = 0.f, ay = 0.f;
    const char* sp = (const char*)support;
    const unsigned loff = (unsigned)lane << 2;   // lane*4 bytes = 2 bf16 feats

    for (int base = beg; base < end; base += 64) {
        int m = end - base; if (m > 64) m = 64;
        long long pk = 0;
        if (lane < m) pk = *(const long long*)&rec[base + lane];  // 1 coalesced load
        int j = 0;
        for (; j + 4 <= m; j += 4) {
            long long p0 = __shfl(pk, j);
            long long p1 = __shfl(pk, j + 1);
            long long p2 = __shfl(pk, j + 2);
            long long p3 = __shfl(pk, j + 3);
            unsigned u0 = *(const unsigned*)(sp + (((unsigned)p0) << 8) + loff);
            unsigned u1 = *(const unsigned*)(sp + (((unsigned)p1) << 8) + loff);
            unsigned u2 = *(const unsigned*)(sp + (((unsigned)p2) << 8) + loff);
            unsigned u3 = *(const unsigned*)(sp + (((unsigned)p3) << 8) + loff);
            float v0 = __int_as_float((int)(p0 >> 32));
            float v1 = __int_as_float((int)(p1 >> 32));
            float v2 = __int_as_float((int)(p2 >> 32));
            float v3 = __int_as_float((int)(p3 >> 32));
            ax += v0 * bf16_lo(u0); ay += v0 * bf16_hi(u0);
            ax += v1 * bf16_lo(u1); ay += v1 * bf16_hi(u1);
            ax += v2 * bf16_lo(u2); ay += v2 * bf16_hi(u2);
            ax += v3 * bf16_lo(u3); ay += v3 * bf16_hi(u3);
        }
        for (; j < m; ++j) {
            long long p = __shfl(pk, j);
            unsigned u = *(const unsigned*)(sp + (((unsigned)p) << 8) + loff);
            float v = __int_as_float((int)(p >> 32));
            ax += v * bf16_lo(u); ay += v * bf16_hi(u);
        }
    }
    float2 b = *(const float2*)(bias + lane * 2);
    *(float2*)(out + (size_t)wid * FDIM + lane * 2) = make_float2(ax + b.x, ay + b.y);
}

// ---------------- fallback (ws too small): atomic scatter ------------------
__global__ __launch_bounds__(256) void init_bias(const float* __restrict__ bias,
                                                 float* __restrict__ out, int n) {
    int idx = blockIdx.x * 256 + threadIdx.x;
    int total = n * (FDIM / 4);
    if (idx < total) {
        int j = (idx & (FDIM / 4 - 1)) * 4;
        float4 b = *(const float4*)(bias + j);
        *(float4*)(out + (size_t)idx * 4) = b;
    }
}

__global__ __launch_bounds__(256) void scatter_bf16(
    const unsigned short* __restrict__ support,
    const int* __restrict__ rows0, const int* __restrict__ cols0, const float* __restrict__ vals0,
    const int* __restrict__ rows1, const int* __restrict__ cols1, const float* __restrict__ vals1,
    float* __restrict__ out, int E) {
    int gid = blockIdx.x * 256 + threadIdx.x;
    int lane = gid & 63;
    int eg = gid >> 6;
    if (eg >= 2 * E) return;
    int r, c; float v;
    if (eg < E) { r = rows0[eg]; c = cols0[eg]; v = vals0[eg]; }
    else        { int e = eg - E; r = rows1[e]; c = cols1[e]; v = vals1[e]; }
    unsigned int u = *(const unsigned int*)(support + (size_t)c * FDIM + lane * 2);
    float sx = bf16_lo(u);
    float sy = bf16_hi(u);
    float* op = out + (size_t)r * FDIM + lane * 2;
    atomicAdd(op,     sx * v);
    atomicAdd(op + 1, sy * v);
}

static inline size_t align256(size_t v) { return (v + 255) & ~(size_t)255; }

extern "C" void kernel_launch(void* const* d_in, const int* in_sizes, int n_in,
                              void* d_out, int out_size, void* d_ws, size_t ws_size,
                              hipStream_t stream) {
    const float* x     = (const float*)d_in[0];
    const float* w     = (const float*)d_in[1];
    const float* bias  = (const float*)d_in[2];
    const float* vals0 = (const float*)d_in[3];
    const float* vals1 = (const float*)d_in[4];
    const int*   rows0 = (const int*)d_in[5];
    const int*   cols0 = (const int*)d_in[6];
    const int*   rows1 = (const int*)d_in[7];
    const int*   cols1 = (const int*)d_in[8];
    const int n = in_sizes[0] / FDIM;
    const int E = in_sizes[3];
    float* out = (float*)d_out;

    const int NB = (n + 255) / 256;

    size_t off = 0;
    unsigned short* support = (unsigned short*)((char*)d_ws + off);
    off = align256(off + (size_t)n * FDIM * 2);
    unsigned short* wt = (unsigned short*)((char*)d_ws + off);
    off = align256(off + (size_t)FDIM * FDIM * 2);
    int*  count  = (int*)((char*)d_ws + off);  off = align256(off + (size_t)n * 4);
    int*  rowptr = (int*)((char*)d_ws + off);  off = align256(off + (size_t)(n + 1) * 4);
    int*  rank   = (int*)((char*)d_ws + off);  off = align256(off + (size_t)2 * E * 4);
    int*  bsum   = (int*)((char*)d_ws + off);  off = align256(off + (size_t)NB * 4);
    int2* rec    = (int2*)((char*)d_ws + off); off = align256(off + (size_t)2 * E * 8);

    wt_conv<<<(FDIM * FDIM) / 256, 256, 0, stream>>>(w, wt);
    gemm_mfma<<<(n + 63) / 64, 256, 0, stream>>>(x, wt, support, n);

    if (off <= ws_size) {
        hipMemsetAsync(count, 0, (size_t)n * 4, stream);
        int eb = (2 * E + 255) / 256;
        hist_rows<<<eb, 256, 0, stream>>>(rows0, rows1, count, rank, E);
        block_sum<<<NB, 256, 0, stream>>>(count, bsum, n);
        scan_bsum<<<1, 256, 0, stream>>>(bsum, NB);
        write_ptr<<<NB, 256, 0, stream>>>(count, bsum, rowptr, n, 2 * E);
        int nper = (n + 7) / 8;
        int ntiles = (2 * E + EPB - 1) / EPB;
        scatter_part<<<ntiles * 8, 256, 0, stream>>>(rows0, cols0, vals0,
                                                     rows1, cols1, vals1,
                                                     rank, rowptr, rec, E, nper);
        pull_csr<<<(n + 3) / 4, 256, 0, stream>>>(support, rowptr, rec, bias, out, n);
    } else {
        int total4 = n * (FDIM / 4);
        init_bias<<<(total4 + 255) / 256, 256, 0, stream>>>(bias, out, n);
        long long tthreads = 2LL * E * 64;
        int blocks = (int)((tthreads + 255) / 256);
        scatter_bf16<<<blocks, 256, 0, stream>>>(support, rows0, cols0, vals0,
                                                 rows1, cols1, vals1, out, E);
    }
}